// Round 1
// baseline (3830.148 us; speedup 1.0000x reference)
//
#include <hip/hip_runtime.h>
#include <cstddef>

#define NB 32      // batch
#define NP 196     // pixels
#define NE 2048    // encoder dim
#define ND 512     // decoder/att/emb dim
#define NV 32000   // vocab
#define NL 21
#define NT 20      // decode steps

// ---------------- setup kernels ----------------

// stable descending argsort of caption lengths (B=32, trivial)
__global__ void k_sort(const int* __restrict__ lens, int* __restrict__ sind, int* __restrict__ dlens)
{
    if (threadIdx.x == 0) {
        int l[NB]; bool used[NB];
        for (int i = 0; i < NB; ++i) { l[i] = lens[i]; used[i] = false; }
        for (int i = 0; i < NB; ++i) {
            int best = -1, bl = -1000000;
            for (int j = 0; j < NB; ++j)
                if (!used[j] && l[j] > bl) { bl = l[j]; best = j; }
            used[best] = true;
            sind[i] = best;
            dlens[i] = bl - 1;
        }
    }
}

__global__ __launch_bounds__(256) void k_mean(const float* __restrict__ enc, const int* __restrict__ sind,
                                              float* __restrict__ mean_enc)
{
    int b = blockIdx.x;
    const float* e = enc + (size_t)sind[b] * NP * NE;
    for (int k = threadIdx.x; k < NE; k += 256) {
        float s = 0.f;
        for (int p = 0; p < NP; ++p) s += e[(size_t)p * NE + k];
        mean_enc[(size_t)b * NE + k] = s * (1.0f / NP);
    }
}

// ---------------- skinny GEMM: C[32][N] = sum_seg A_s @ W_s^T (+biases) ----------------
// weight row for global n: n < Nsplit ? Wa + n*Kseg : Wb + (n-Nsplit)*Kseg
// split-K over gridDim.y (partial outputs at C + y*cystride; bias only on y==0)

__device__ __forceinline__ void skinny_seg(
    const float* __restrict__ A, int lda, int kbeg, int kend,
    const float* __restrict__ Wa, const float* __restrict__ Wb, int Nsplit, int Kseg,
    int n0, float acc[4][2], float (*As)[32], float (*Ws)[33])
{
    int tid = threadIdx.x;
    int lb = tid / 8, lkq = tid % 8;          // A-load mapping
    int b4 = (tid / 32) * 4, nl = (tid % 32) * 2;
    for (int kt = kbeg; kt < kend; kt += 32) {
        float4 a4 = *reinterpret_cast<const float4*>(A + (size_t)lb * lda + kt + lkq * 4);
        As[lkq * 4 + 0][lb] = a4.x; As[lkq * 4 + 1][lb] = a4.y;
        As[lkq * 4 + 2][lb] = a4.z; As[lkq * 4 + 3][lb] = a4.w;
        #pragma unroll
        for (int r = 0; r < 2; ++r) {
            int s = tid + r * 256;
            int n_l = s / 8, kq = s % 8;
            int ng = n0 + n_l;
            const float* wrow = (ng < Nsplit) ? (Wa + (size_t)ng * Kseg)
                                              : (Wb + (size_t)(ng - Nsplit) * Kseg);
            float4 w4 = *reinterpret_cast<const float4*>(wrow + kt + kq * 4);
            Ws[n_l][kq * 4 + 0] = w4.x; Ws[n_l][kq * 4 + 1] = w4.y;
            Ws[n_l][kq * 4 + 2] = w4.z; Ws[n_l][kq * 4 + 3] = w4.w;
        }
        __syncthreads();
        #pragma unroll
        for (int k = 0; k < 32; ++k) {
            float4 av = *reinterpret_cast<const float4*>(&As[k][b4]);
            float w0 = Ws[nl][k], w1 = Ws[nl + 1][k];
            acc[0][0] += av.x * w0; acc[0][1] += av.x * w1;
            acc[1][0] += av.y * w0; acc[1][1] += av.y * w1;
            acc[2][0] += av.z * w0; acc[2][1] += av.z * w1;
            acc[3][0] += av.w * w0; acc[3][1] += av.w * w1;
        }
        __syncthreads();
    }
}

__global__ __launch_bounds__(256) void gemm_skinny(
    const float* A0, int lda0, int K0, const float* W0a, const float* W0b,
    const float* A1, int lda1, int K1, const float* W1a, const float* W1b,
    const float* ba, const float* bb, const float* be,
    int Nsplit, int N, float* C, int ldc, int cystride, int KS)
{
    __shared__ float As[32][32];
    __shared__ float Ws[64][33];
    int n0 = blockIdx.x * 64;
    int y = blockIdx.y;
    float acc[4][2] = {};
    skinny_seg(A0, lda0, y * (K0 / KS), (y + 1) * (K0 / KS), W0a, W0b, Nsplit, K0, n0, acc, As, Ws);
    if (A1) skinny_seg(A1, lda1, y * (K1 / KS), (y + 1) * (K1 / KS), W1a, W1b, Nsplit, K1, n0, acc, As, Ws);
    int tid = threadIdx.x;
    int b4 = (tid / 32) * 4, nl = (tid % 32) * 2;
    #pragma unroll
    for (int j = 0; j < 2; ++j) {
        int ng = n0 + nl + j;
        float bias = 0.f;
        if (y == 0) {
            if (ng < Nsplit) { if (ba) bias += ba[ng]; }
            else             { if (bb) bias += bb[ng - Nsplit]; }
            if (be) bias += be[ng];
        }
        #pragma unroll
        for (int i = 0; i < 4; ++i)
            C[(size_t)y * cystride + (size_t)(b4 + i) * ldc + ng] = acc[i][j] + bias;
    }
}

// ---------------- big GEMM: 64x64 tile, fp32, C = A @ W^T + bias ----------------
// MODE 0: att1  (A rows indirected through sind over (b,p); C row-major ldc=N)
// MODE 1: preds (A = h_seq rows (t*32+b); epilogue remaps to out[b][t][v] with mask)

template<int MODE>
__global__ __launch_bounds__(256) void gemm_big(
    const float* __restrict__ A, const float* __restrict__ W, const float* __restrict__ bias,
    float* __restrict__ C, int M, int N, int K,
    const int* __restrict__ sind, const int* __restrict__ dlens)
{
    __shared__ float As[16][64];
    __shared__ float Ws[16][64];
    int bn0 = blockIdx.x * 64, bm0 = blockIdx.y * 64;
    int tid = threadIdx.x;
    int ty = tid / 16, tx = tid % 16;
    int lm = tid / 4, lk = (tid % 4) * 4;
    const float* arow;
    int mg = bm0 + lm;
    if (MODE == 0) {
        int bidx = mg / NP, p = mg - bidx * NP;
        arow = A + ((size_t)sind[bidx] * NP + p) * (size_t)K;
    } else {
        arow = A + (size_t)mg * K;
    }
    const float* wrow = W + (size_t)(bn0 + lm) * K;
    float acc[4][4] = {};
    for (int kt = 0; kt < K; kt += 16) {
        float4 a4 = *reinterpret_cast<const float4*>(arow + kt + lk);
        float4 w4 = *reinterpret_cast<const float4*>(wrow + kt + lk);
        As[lk + 0][lm] = a4.x; As[lk + 1][lm] = a4.y; As[lk + 2][lm] = a4.z; As[lk + 3][lm] = a4.w;
        Ws[lk + 0][lm] = w4.x; Ws[lk + 1][lm] = w4.y; Ws[lk + 2][lm] = w4.z; Ws[lk + 3][lm] = w4.w;
        __syncthreads();
        #pragma unroll
        for (int k = 0; k < 16; ++k) {
            float4 av = *reinterpret_cast<const float4*>(&As[k][ty * 4]);
            float4 wv = *reinterpret_cast<const float4*>(&Ws[k][tx * 4]);
            acc[0][0] += av.x * wv.x; acc[0][1] += av.x * wv.y; acc[0][2] += av.x * wv.z; acc[0][3] += av.x * wv.w;
            acc[1][0] += av.y * wv.x; acc[1][1] += av.y * wv.y; acc[1][2] += av.y * wv.z; acc[1][3] += av.y * wv.w;
            acc[2][0] += av.z * wv.x; acc[2][1] += av.z * wv.y; acc[2][2] += av.z * wv.z; acc[2][3] += av.z * wv.w;
            acc[3][0] += av.w * wv.x; acc[3][1] += av.w * wv.y; acc[3][2] += av.w * wv.z; acc[3][3] += av.w * wv.w;
        }
        __syncthreads();
    }
    #pragma unroll
    for (int i = 0; i < 4; ++i) {
        int m = bm0 + ty * 4 + i;
        int n = bn0 + tx * 4;
        float4 o;
        o.x = acc[i][0] + bias[n + 0];
        o.y = acc[i][1] + bias[n + 1];
        o.z = acc[i][2] + bias[n + 2];
        o.w = acc[i][3] + bias[n + 3];
        if (MODE == 0) {
            *reinterpret_cast<float4*>(C + (size_t)m * N + n) = o;
        } else {
            int tt = m >> 5, b = m & 31;
            if (tt >= dlens[b]) { o.x = 0.f; o.y = 0.f; o.z = 0.f; o.w = 0.f; }
            *reinterpret_cast<float4*>(C + ((size_t)b * NT + tt) * NV + n) = o;
        }
    }
}

// ---------------- per-step attention kernel (one block per batch element) ----------------
// e = relu(att1[b] + att2) . w_fa + b_fa ; alpha = softmax_p(e) ; awe = alpha . enc[b]
// x[b] = [ emb_t , sigmoid(gate_pre) * awe ]

__global__ __launch_bounds__(256) void k_s1(
    const float* __restrict__ enc, const int* __restrict__ sind, const int* __restrict__ dlens,
    const int* __restrict__ caps, const float* __restrict__ emb_W,
    const float* __restrict__ att1, const float* __restrict__ attgate,
    const float* __restrict__ w_fa, const float* __restrict__ b_fa,
    float* __restrict__ x, float* __restrict__ out_alpha, int t)
{
    __shared__ float att2s[ND];
    __shared__ float wfas[ND];
    __shared__ float es[NP];
    __shared__ float red[256];
    int b = blockIdx.x, tid = threadIdx.x;
    const float* ag = attgate + (size_t)b * 2560;
    for (int d = tid; d < ND; d += 256) { att2s[d] = ag[d]; wfas[d] = w_fa[d]; }
    __syncthreads();
    int wv = tid >> 6, lane = tid & 63;
    const float* a1 = att1 + (size_t)b * NP * ND;
    for (int p = wv; p < NP; p += 4) {
        float s = 0.f;
        const float* row = a1 + (size_t)p * ND;
        #pragma unroll
        for (int j = 0; j < 8; ++j) {
            int d = lane + 64 * j;
            float v = row[d] + att2s[d];
            v = fmaxf(v, 0.f);
            s += v * wfas[d];
        }
        for (int off = 32; off > 0; off >>= 1) s += __shfl_down(s, off);
        if (lane == 0) es[p] = s + b_fa[0];
    }
    __syncthreads();
    // softmax over P
    float m = -1e30f;
    for (int p = tid; p < NP; p += 256) m = fmaxf(m, es[p]);
    red[tid] = m; __syncthreads();
    for (int s = 128; s > 0; s >>= 1) { if (tid < s) red[tid] = fmaxf(red[tid], red[tid + s]); __syncthreads(); }
    m = red[0]; __syncthreads();
    float sm = 0.f;
    for (int p = tid; p < NP; p += 256) { float v = expf(es[p] - m); es[p] = v; sm += v; }
    red[tid] = sm; __syncthreads();
    for (int s = 128; s > 0; s >>= 1) { if (tid < s) red[tid] += red[tid + s]; __syncthreads(); }
    float inv = 1.0f / red[0];
    bool live = (t < dlens[b]);
    for (int p = tid; p < NP; p += 256) {
        float al = es[p] * inv;
        es[p] = al;
        out_alpha[((size_t)b * NT + t) * NP + p] = live ? al : 0.f;
    }
    __syncthreads();
    // embedding gather
    const float* er = emb_W + (size_t)caps[sind[b] * NL + t] * ND;
    float* xb = x + (size_t)b * 2560;
    for (int d = tid; d < ND; d += 256) xb[d] = er[d];
    // awe + gate
    const float* eb = enc + (size_t)sind[b] * NP * NE;
    for (int k = tid; k < NE; k += 256) {
        float s = 0.f;
        for (int p = 0; p < NP; ++p) s += es[p] * eb[(size_t)p * NE + k];
        float gpre = ag[ND + k];
        float gate = 1.0f / (1.0f + expf(-gpre));
        xb[ND + k] = gate * s;
    }
}

// ---------------- split-K reduce + LSTM cell ----------------
__global__ void k_cell(const float* __restrict__ gpart, const int* __restrict__ dlens,
                       float* __restrict__ hc, float* __restrict__ hseq, int t)
{
    int b = blockIdx.x;
    for (int d = threadIdx.x; d < ND; d += blockDim.x) {
        float a[4];
        #pragma unroll
        for (int q = 0; q < 4; ++q) {
            float s = 0.f;
            #pragma unroll
            for (int ks = 0; ks < 4; ++ks)
                s += gpart[((size_t)ks * NB + b) * 2048 + q * ND + d];
            a[q] = s;
        }
        float ig = 1.f / (1.f + expf(-a[0]));
        float fg = 1.f / (1.f + expf(-a[1]));
        float gg = tanhf(a[2]);
        float og = 1.f / (1.f + expf(-a[3]));
        float c_old = hc[(size_t)b * 1024 + ND + d];
        float c_new = fg * c_old + ig * gg;
        float h_new = og * tanhf(c_new);
        hseq[((size_t)t * NB + b) * ND + d] = h_new;   // pre-mask h feeds preds
        if (t < dlens[b]) {
            hc[(size_t)b * 1024 + d] = h_new;
            hc[(size_t)b * 1024 + ND + d] = c_new;
        }
    }
}

// ---------------- launcher ----------------
extern "C" void kernel_launch(void* const* d_in, const int* in_sizes, int n_in,
                              void* d_out, int out_size, void* d_ws, size_t ws_size,
                              hipStream_t stream)
{
    const float* enc   = (const float*)d_in[0];
    const int*   caps  = (const int*)d_in[1];
    const int*   clens = (const int*)d_in[2];
    const float* emb_W = (const float*)d_in[3];
    const float* W_ea  = (const float*)d_in[4];
    const float* b_ea  = (const float*)d_in[5];
    const float* W_da  = (const float*)d_in[6];
    const float* b_da  = (const float*)d_in[7];
    const float* w_fa  = (const float*)d_in[8];
    const float* b_fa  = (const float*)d_in[9];
    const float* W_ih  = (const float*)d_in[10];
    const float* b_ih  = (const float*)d_in[11];
    const float* W_hh  = (const float*)d_in[12];
    const float* b_hh  = (const float*)d_in[13];
    const float* W_h0  = (const float*)d_in[14];
    const float* b_h0  = (const float*)d_in[15];
    const float* W_c0  = (const float*)d_in[16];
    const float* b_c0  = (const float*)d_in[17];
    const float* W_fb  = (const float*)d_in[18];
    const float* b_fb  = (const float*)d_in[19];
    const float* W_fc  = (const float*)d_in[20];
    const float* b_fc  = (const float*)d_in[21];

    float* out = (float*)d_out;
    float* out_alpha = out + (size_t)NB * NT * NV;

    // workspace layout (floats; first 64 slots hold ints) — ~16.3 MB total
    int*   iws   = (int*)d_ws;
    int*   sind  = iws;
    int*   dlens = iws + 32;
    float* wf    = (float*)d_ws;
    float* mean_enc = wf + 64;
    float* hc    = mean_enc + NB * NE;                  // h = [b][0:512], c = [b][512:1024]
    float* att1  = hc + NB * 1024;
    float* attg  = att1 + (size_t)NB * NP * ND;         // [b][0:512]=att2pre, [512:2560]=gate_pre
    float* x     = attg + NB * 2560;                    // [b][0:512]=emb, [512:2560]=gate*awe
    float* gpart = x + NB * 2560;                       // [4][32][2048] split-K partials
    float* hseq  = gpart + 4 * NB * 2048;               // [t][b][512]

    k_sort<<<1, 64, 0, stream>>>(clens, sind, dlens);
    k_mean<<<NB, 256, 0, stream>>>(enc, sind, mean_enc);
    // h0 | c0
    gemm_skinny<<<dim3(16, 1), 256, 0, stream>>>(mean_enc, NE, NE, W_h0, W_c0,
                                                 nullptr, 0, 0, nullptr, nullptr,
                                                 b_h0, b_c0, nullptr,
                                                 512, 1024, hc, 1024, 0, 1);
    // att1 = enc_sorted @ W_ea^T + b_ea
    gemm_big<0><<<dim3(ND / 64, (NB * NP) / 64), 256, 0, stream>>>(
        enc, W_ea, b_ea, att1, NB * NP, ND, NE, sind, dlens);

    for (int t = 0; t < NT; ++t) {
        // [att2pre | gate_pre] = h @ [W_da ; W_fb]^T + [b_da ; b_fb]
        gemm_skinny<<<dim3(40, 1), 256, 0, stream>>>(hc, 1024, 512, W_da, W_fb,
                                                     nullptr, 0, 0, nullptr, nullptr,
                                                     b_da, b_fb, nullptr,
                                                     512, 2560, attg, 2560, 0, 1);
        k_s1<<<NB, 256, 0, stream>>>(enc, sind, dlens, caps, emb_W, att1, attg,
                                     w_fa, b_fa, x, out_alpha, t);
        // g = x @ W_ih^T + h @ W_hh^T + b_ih + b_hh   (split-K=4 partials)
        gemm_skinny<<<dim3(32, 4), 256, 0, stream>>>(x, 2560, 2560, W_ih, W_ih,
                                                     hc, 1024, 512, W_hh, W_hh,
                                                     b_ih, nullptr, b_hh,
                                                     2048, 2048, gpart, 2048, NB * 2048, 4);
        k_cell<<<NB, 128, 0, stream>>>(gpart, dlens, hc, hseq, t);
    }

    // predictions = h_seq @ W_fc^T + b_fc, masked, remapped to [b][t][v]
    gemm_big<1><<<dim3(NV / 64, (NB * NT) / 64), 256, 0, stream>>>(
        hseq, W_fc, b_fc, out, NB * NT, NV, ND, sind, dlens);
}

// Round 2
// 2461.636 us; speedup vs baseline: 1.5559x; 1.5559x over previous
//
#include <hip/hip_runtime.h>
#include <cstddef>

#define NB 32      // batch
#define NP 196     // pixels
#define NE 2048    // encoder dim
#define ND 512     // decoder/att/emb dim
#define NV 32000   // vocab
#define NL 21
#define NT 20      // decode steps

// ---------------- setup kernels ----------------

// stable descending argsort via rank counting (wave-parallel)
__global__ void k_sort(const int* __restrict__ lens, int* __restrict__ sind, int* __restrict__ dlens)
{
    int i = threadIdx.x;
    if (i < NB) {
        int li = lens[i];
        int r = 0;
        for (int j = 0; j < NB; ++j) {
            int lj = lens[j];
            if (lj > li || (lj == li && j < i)) ++r;
        }
        sind[r] = i;
        dlens[r] = li - 1;
    }
}

// mean over P for a 256-wide k-chunk; grid (NE/256, NB)
__global__ __launch_bounds__(256) void k_mean(const float* __restrict__ enc, const int* __restrict__ sind,
                                              float* __restrict__ mean_enc)
{
    int b = blockIdx.y;
    int k = blockIdx.x * 256 + threadIdx.x;
    const float* e = enc + (size_t)sind[b] * NP * NE + k;
    float s0 = 0.f, s1 = 0.f, s2 = 0.f, s3 = 0.f;
    for (int p = 0; p < NP - 3; p += 4) {
        s0 += e[(size_t)(p + 0) * NE];
        s1 += e[(size_t)(p + 1) * NE];
        s2 += e[(size_t)(p + 2) * NE];
        s3 += e[(size_t)(p + 3) * NE];
    }
    // tail (NP = 196 = 4*49, no tail actually)
    mean_enc[(size_t)b * NE + k] = (s0 + s1 + s2 + s3) * (1.0f / NP);
}

// ---------------- skinny GEMM: C[32][N] = sum_seg A_s @ W_s^T (+biases) ----------------

__device__ __forceinline__ void skinny_seg(
    const float* __restrict__ A, int lda, int kbeg, int kend,
    const float* __restrict__ Wa, const float* __restrict__ Wb, int Nsplit, int Kseg,
    int n0, float acc[4][2], float (*As)[32], float (*Ws)[33])
{
    int tid = threadIdx.x;
    int lb = tid / 8, lkq = tid % 8;
    int b4 = (tid / 32) * 4, nl = (tid % 32) * 2;
    for (int kt = kbeg; kt < kend; kt += 32) {
        float4 a4 = *reinterpret_cast<const float4*>(A + (size_t)lb * lda + kt + lkq * 4);
        As[lkq * 4 + 0][lb] = a4.x; As[lkq * 4 + 1][lb] = a4.y;
        As[lkq * 4 + 2][lb] = a4.z; As[lkq * 4 + 3][lb] = a4.w;
        #pragma unroll
        for (int r = 0; r < 2; ++r) {
            int s = tid + r * 256;
            int n_l = s / 8, kq = s % 8;
            int ng = n0 + n_l;
            const float* wrow = (ng < Nsplit) ? (Wa + (size_t)ng * Kseg)
                                              : (Wb + (size_t)(ng - Nsplit) * Kseg);
            float4 w4 = *reinterpret_cast<const float4*>(wrow + kt + kq * 4);
            Ws[n_l][kq * 4 + 0] = w4.x; Ws[n_l][kq * 4 + 1] = w4.y;
            Ws[n_l][kq * 4 + 2] = w4.z; Ws[n_l][kq * 4 + 3] = w4.w;
        }
        __syncthreads();
        #pragma unroll
        for (int k = 0; k < 32; ++k) {
            float4 av = *reinterpret_cast<const float4*>(&As[k][b4]);
            float w0 = Ws[nl][k], w1 = Ws[nl + 1][k];
            acc[0][0] += av.x * w0; acc[0][1] += av.x * w1;
            acc[1][0] += av.y * w0; acc[1][1] += av.y * w1;
            acc[2][0] += av.z * w0; acc[2][1] += av.z * w1;
            acc[3][0] += av.w * w0; acc[3][1] += av.w * w1;
        }
        __syncthreads();
    }
}

__global__ __launch_bounds__(256) void gemm_skinny(
    const float* A0, int lda0, int K0, const float* W0a, const float* W0b,
    const float* A1, int lda1, int K1, const float* W1a, const float* W1b,
    const float* ba, const float* bb, const float* be,
    int Nsplit, int N, float* C, int ldc, int cystride, int KS)
{
    __shared__ float As[32][32];
    __shared__ float Ws[64][33];
    int n0 = blockIdx.x * 64;
    int y = blockIdx.y;
    float acc[4][2] = {};
    skinny_seg(A0, lda0, y * (K0 / KS), (y + 1) * (K0 / KS), W0a, W0b, Nsplit, K0, n0, acc, As, Ws);
    if (A1) skinny_seg(A1, lda1, y * (K1 / KS), (y + 1) * (K1 / KS), W1a, W1b, Nsplit, K1, n0, acc, As, Ws);
    int tid = threadIdx.x;
    int b4 = (tid / 32) * 4, nl = (tid % 32) * 2;
    #pragma unroll
    for (int j = 0; j < 2; ++j) {
        int ng = n0 + nl + j;
        float bias = 0.f;
        if (y == 0) {
            if (ng < Nsplit) { if (ba) bias += ba[ng]; }
            else             { if (bb) bias += bb[ng - Nsplit]; }
            if (be) bias += be[ng];
        }
        #pragma unroll
        for (int i = 0; i < 4; ++i)
            C[(size_t)y * cystride + (size_t)(b4 + i) * ldc + ng] = acc[i][j] + bias;
    }
}

// ---------------- att1 GEMM: 64x64 tile fp32, A rows indirected through sind ----------------
__global__ __launch_bounds__(256) void gemm_att1(
    const float* __restrict__ A, const float* __restrict__ W, const float* __restrict__ bias,
    float* __restrict__ C, const int* __restrict__ sind)
{
    __shared__ float As[16][64];
    __shared__ float Ws[16][64];
    int bn0 = blockIdx.x * 64, bm0 = blockIdx.y * 64;
    int tid = threadIdx.x;
    int ty = tid / 16, tx = tid % 16;
    int lm = tid / 4, lk = (tid % 4) * 4;
    int mg = bm0 + lm;
    int bidx = mg / NP, p = mg - bidx * NP;
    const float* arow = A + ((size_t)sind[bidx] * NP + p) * (size_t)NE;
    const float* wrow = W + (size_t)(bn0 + lm) * NE;
    float acc[4][4] = {};
    for (int kt = 0; kt < NE; kt += 16) {
        float4 a4 = *reinterpret_cast<const float4*>(arow + kt + lk);
        float4 w4 = *reinterpret_cast<const float4*>(wrow + kt + lk);
        As[lk + 0][lm] = a4.x; As[lk + 1][lm] = a4.y; As[lk + 2][lm] = a4.z; As[lk + 3][lm] = a4.w;
        Ws[lk + 0][lm] = w4.x; Ws[lk + 1][lm] = w4.y; Ws[lk + 2][lm] = w4.z; Ws[lk + 3][lm] = w4.w;
        __syncthreads();
        #pragma unroll
        for (int k = 0; k < 16; ++k) {
            float4 av = *reinterpret_cast<const float4*>(&As[k][ty * 4]);
            float4 wv = *reinterpret_cast<const float4*>(&Ws[k][tx * 4]);
            acc[0][0] += av.x * wv.x; acc[0][1] += av.x * wv.y; acc[0][2] += av.x * wv.z; acc[0][3] += av.x * wv.w;
            acc[1][0] += av.y * wv.x; acc[1][1] += av.y * wv.y; acc[1][2] += av.y * wv.z; acc[1][3] += av.y * wv.w;
            acc[2][0] += av.z * wv.x; acc[2][1] += av.z * wv.y; acc[2][2] += av.z * wv.z; acc[2][3] += av.z * wv.w;
            acc[3][0] += av.w * wv.x; acc[3][1] += av.w * wv.y; acc[3][2] += av.w * wv.z; acc[3][3] += av.w * wv.w;
        }
        __syncthreads();
    }
    #pragma unroll
    for (int i = 0; i < 4; ++i) {
        int m = bm0 + ty * 4 + i;
        int n = bn0 + tx * 4;
        float4 o;
        o.x = acc[i][0] + bias[n + 0];
        o.y = acc[i][1] + bias[n + 1];
        o.z = acc[i][2] + bias[n + 2];
        o.w = acc[i][3] + bias[n + 3];
        *reinterpret_cast<float4*>(C + (size_t)m * ND + n) = o;
    }
}

// ---------------- preds GEMM: block owns N-tile, loops all M-tiles (W stays L2-hot) ----------------
__global__ __launch_bounds__(256) void gemm_preds(
    const float* __restrict__ A, const float* __restrict__ W, const float* __restrict__ bias,
    float* __restrict__ C, const int* __restrict__ dlens)
{
    __shared__ float As[16][64];
    __shared__ float Ws[16][64];
    int bn0 = blockIdx.x * 64;
    int tid = threadIdx.x;
    int ty = tid / 16, tx = tid % 16;
    int lm = tid / 4, lk = (tid % 4) * 4;
    const float* wrow = W + (size_t)(bn0 + lm) * ND;
    int n = bn0 + tx * 4;
    float4 bb = *reinterpret_cast<const float4*>(bias + n);
    for (int mt = 0; mt < (NB * NT) / 64; ++mt) {
        const float* arow = A + (size_t)(mt * 64 + lm) * ND;
        float acc[4][4] = {};
        for (int kt = 0; kt < ND; kt += 16) {
            float4 a4 = *reinterpret_cast<const float4*>(arow + kt + lk);
            float4 w4 = *reinterpret_cast<const float4*>(wrow + kt + lk);
            As[lk + 0][lm] = a4.x; As[lk + 1][lm] = a4.y; As[lk + 2][lm] = a4.z; As[lk + 3][lm] = a4.w;
            Ws[lk + 0][lm] = w4.x; Ws[lk + 1][lm] = w4.y; Ws[lk + 2][lm] = w4.z; Ws[lk + 3][lm] = w4.w;
            __syncthreads();
            #pragma unroll
            for (int k = 0; k < 16; ++k) {
                float4 av = *reinterpret_cast<const float4*>(&As[k][ty * 4]);
                float4 wv = *reinterpret_cast<const float4*>(&Ws[k][tx * 4]);
                acc[0][0] += av.x * wv.x; acc[0][1] += av.x * wv.y; acc[0][2] += av.x * wv.z; acc[0][3] += av.x * wv.w;
                acc[1][0] += av.y * wv.x; acc[1][1] += av.y * wv.y; acc[1][2] += av.y * wv.z; acc[1][3] += av.y * wv.w;
                acc[2][0] += av.z * wv.x; acc[2][1] += av.z * wv.y; acc[2][2] += av.z * wv.z; acc[2][3] += av.z * wv.w;
                acc[3][0] += av.w * wv.x; acc[3][1] += av.w * wv.y; acc[3][2] += av.w * wv.z; acc[3][3] += av.w * wv.w;
            }
            __syncthreads();
        }
        #pragma unroll
        for (int i = 0; i < 4; ++i) {
            int m = mt * 64 + ty * 4 + i;
            int tt = m >> 5, b = m & 31;
            float4 o;
            o.x = acc[i][0] + bb.x;
            o.y = acc[i][1] + bb.y;
            o.z = acc[i][2] + bb.z;
            o.w = acc[i][3] + bb.w;
            if (tt >= dlens[b]) { o.x = 0.f; o.y = 0.f; o.z = 0.f; o.w = 0.f; }
            *reinterpret_cast<float4*>(C + ((size_t)b * NT + tt) * NV + n) = o;
        }
    }
}

// ---------------- per-step: e scores (grid 7 x 32, 224 blocks) ----------------
__global__ __launch_bounds__(256) void k_e(
    const float* __restrict__ att1, const float* __restrict__ attg,
    const float* __restrict__ w_fa, const float* __restrict__ b_fa,
    float* __restrict__ e)
{
    __shared__ float att2s[ND];
    __shared__ float wfas[ND];
    int b = blockIdx.y, tid = threadIdx.x;
    const float* ag = attg + (size_t)b * 2560;
    for (int d = tid; d < ND; d += 256) { att2s[d] = ag[d]; wfas[d] = w_fa[d]; }
    __syncthreads();
    int wv = tid >> 6, lane = tid & 63;
    int p0 = blockIdx.x * 28;
    const float* a1 = att1 + ((size_t)b * NP + p0) * ND;
    #pragma unroll
    for (int i = 0; i < 7; ++i) {
        int p = wv + 4 * i;
        const float* row = a1 + (size_t)p * ND;
        float s = 0.f;
        #pragma unroll
        for (int j = 0; j < 2; ++j) {
            int d = j * 256 + lane * 4;
            float4 v = *reinterpret_cast<const float4*>(row + d);
            float4 a2 = *reinterpret_cast<const float4*>(&att2s[d]);
            float4 wf = *reinterpret_cast<const float4*>(&wfas[d]);
            s += fmaxf(v.x + a2.x, 0.f) * wf.x;
            s += fmaxf(v.y + a2.y, 0.f) * wf.y;
            s += fmaxf(v.z + a2.z, 0.f) * wf.z;
            s += fmaxf(v.w + a2.w, 0.f) * wf.w;
        }
        for (int off = 32; off > 0; off >>= 1) s += __shfl_down(s, off);
        if (lane == 0) e[(size_t)b * NP + p0 + p] = s + b_fa[0];
    }
}

// ---------------- per-step: softmax (in-block, redundant per chunk) + awe + gate + x ----------------
// grid (NE/256, NB)
__global__ __launch_bounds__(256) void k_awe(
    const float* __restrict__ enc, const int* __restrict__ sind, const int* __restrict__ dlens,
    const int* __restrict__ caps, const float* __restrict__ emb_W,
    const float* __restrict__ e, const float* __restrict__ attg,
    float* __restrict__ x, float* __restrict__ out_alpha, int t)
{
    __shared__ float es[NP];
    __shared__ float red[256];
    int b = blockIdx.y, y = blockIdx.x, tid = threadIdx.x;
    float m = -1e30f;
    if (tid < NP) { float v = e[(size_t)b * NP + tid]; es[tid] = v; m = v; }
    red[tid] = m; __syncthreads();
    for (int s = 128; s > 0; s >>= 1) { if (tid < s) red[tid] = fmaxf(red[tid], red[tid + s]); __syncthreads(); }
    m = red[0]; __syncthreads();
    float sm = 0.f;
    if (tid < NP) { float v = expf(es[tid] - m); es[tid] = v; sm = v; }
    red[tid] = sm; __syncthreads();
    for (int s = 128; s > 0; s >>= 1) { if (tid < s) red[tid] += red[tid + s]; __syncthreads(); }
    float inv = 1.0f / red[0]; __syncthreads();
    if (tid < NP) es[tid] *= inv;
    __syncthreads();

    int k = y * 256 + tid;
    const float* eb = enc + (size_t)sind[b] * NP * NE + k;
    float s0 = 0.f, s1 = 0.f, s2 = 0.f, s3 = 0.f;
    #pragma unroll 4
    for (int p = 0; p < NP - 3; p += 4) {
        s0 += es[p + 0] * eb[(size_t)(p + 0) * NE];
        s1 += es[p + 1] * eb[(size_t)(p + 1) * NE];
        s2 += es[p + 2] * eb[(size_t)(p + 2) * NE];
        s3 += es[p + 3] * eb[(size_t)(p + 3) * NE];
    }
    float s = (s0 + s1) + (s2 + s3);
    const float* ag = attg + (size_t)b * 2560;
    float gate = 1.0f / (1.0f + expf(-ag[ND + k]));
    float* xb = x + (size_t)b * 2560;
    xb[ND + k] = gate * s;
    if (y == 0) {
        bool live = (t < dlens[b]);
        if (tid < NP) out_alpha[((size_t)b * NT + t) * NP + tid] = live ? es[tid] : 0.f;
        const float* er = emb_W + (size_t)caps[sind[b] * NL + t] * ND;
        for (int d = tid; d < ND; d += 256) xb[d] = er[d];
    }
}

// ---------------- split-K reduce + LSTM cell ----------------
__global__ void k_cell(const float* __restrict__ gpart, const int* __restrict__ dlens,
                       float* __restrict__ hc, float* __restrict__ hseq, int t)
{
    int b = blockIdx.x;
    for (int d = threadIdx.x; d < ND; d += blockDim.x) {
        float a[4];
        #pragma unroll
        for (int q = 0; q < 4; ++q) {
            float s = 0.f;
            #pragma unroll
            for (int ks = 0; ks < 4; ++ks)
                s += gpart[((size_t)ks * NB + b) * 2048 + q * ND + d];
            a[q] = s;
        }
        float ig = 1.f / (1.f + expf(-a[0]));
        float fg = 1.f / (1.f + expf(-a[1]));
        float gg = tanhf(a[2]);
        float og = 1.f / (1.f + expf(-a[3]));
        float c_old = hc[(size_t)b * 1024 + ND + d];
        float c_new = fg * c_old + ig * gg;
        float h_new = og * tanhf(c_new);
        hseq[((size_t)t * NB + b) * ND + d] = h_new;
        if (t < dlens[b]) {
            hc[(size_t)b * 1024 + d] = h_new;
            hc[(size_t)b * 1024 + ND + d] = c_new;
        }
    }
}

// ---------------- launcher ----------------
extern "C" void kernel_launch(void* const* d_in, const int* in_sizes, int n_in,
                              void* d_out, int out_size, void* d_ws, size_t ws_size,
                              hipStream_t stream)
{
    const float* enc   = (const float*)d_in[0];
    const int*   caps  = (const int*)d_in[1];
    const int*   clens = (const int*)d_in[2];
    const float* emb_W = (const float*)d_in[3];
    const float* W_ea  = (const float*)d_in[4];
    const float* b_ea  = (const float*)d_in[5];
    const float* W_da  = (const float*)d_in[6];
    const float* b_da  = (const float*)d_in[7];
    const float* w_fa  = (const float*)d_in[8];
    const float* b_fa  = (const float*)d_in[9];
    const float* W_ih  = (const float*)d_in[10];
    const float* b_ih  = (const float*)d_in[11];
    const float* W_hh  = (const float*)d_in[12];
    const float* b_hh  = (const float*)d_in[13];
    const float* W_h0  = (const float*)d_in[14];
    const float* b_h0  = (const float*)d_in[15];
    const float* W_c0  = (const float*)d_in[16];
    const float* b_c0  = (const float*)d_in[17];
    const float* W_fb  = (const float*)d_in[18];
    const float* b_fb  = (const float*)d_in[19];
    const float* W_fc  = (const float*)d_in[20];
    const float* b_fc  = (const float*)d_in[21];

    float* out = (float*)d_out;
    float* out_alpha = out + (size_t)NB * NT * NV;

    int*   iws   = (int*)d_ws;
    int*   sind  = iws;
    int*   dlens = iws + 32;
    float* wf    = (float*)d_ws;
    float* mean_enc = wf + 64;
    float* hc    = mean_enc + NB * NE;
    float* att1  = hc + NB * 1024;
    float* attg  = att1 + (size_t)NB * NP * ND;
    float* x     = attg + NB * 2560;
    float* gpart = x + NB * 2560;
    float* hseq  = gpart + 4 * NB * 2048;
    float* e     = hseq + NT * NB * ND;          // [32][196]

    k_sort<<<1, 64, 0, stream>>>(clens, sind, dlens);
    k_mean<<<dim3(NE / 256, NB), 256, 0, stream>>>(enc, sind, mean_enc);
    gemm_skinny<<<dim3(16, 1), 256, 0, stream>>>(mean_enc, NE, NE, W_h0, W_c0,
                                                 nullptr, 0, 0, nullptr, nullptr,
                                                 b_h0, b_c0, nullptr,
                                                 512, 1024, hc, 1024, 0, 1);
    gemm_att1<<<dim3(ND / 64, (NB * NP) / 64), 256, 0, stream>>>(enc, W_ea, b_ea, att1, sind);

    for (int t = 0; t < NT; ++t) {
        gemm_skinny<<<dim3(40, 1), 256, 0, stream>>>(hc, 1024, 512, W_da, W_fb,
                                                     nullptr, 0, 0, nullptr, nullptr,
                                                     b_da, b_fb, nullptr,
                                                     512, 2560, attg, 2560, 0, 1);
        k_e<<<dim3(7, NB), 256, 0, stream>>>(att1, attg, w_fa, b_fa, e);
        k_awe<<<dim3(NE / 256, NB), 256, 0, stream>>>(enc, sind, dlens, caps, emb_W,
                                                      e, attg, x, out_alpha, t);
        gemm_skinny<<<dim3(32, 4), 256, 0, stream>>>(x, 2560, 2560, W_ih, W_ih,
                                                     hc, 1024, 512, W_hh, W_hh,
                                                     b_ih, nullptr, b_hh,
                                                     2048, 2048, gpart, 2048, NB * 2048, 4);
        k_cell<<<NB, 128, 0, stream>>>(gpart, dlens, hc, hseq, t);
    }

    gemm_preds<<<dim3(NV / 64), 256, 0, stream>>>(hseq, W_fc, b_fc, out, dlens);
}